// Round 6
// baseline (461.184 us; speedup 1.0000x reference)
//
#include <hip/hip_runtime.h>
#include <math.h>

#define N_NODES 100000
#define N_EDGES 2500000
#define N_GRAPHS 512
#define IN_DIM 14
#define HID 32
#define CAP 64        // per-node slot capacity; degree ~ Poisson(25), max ~55
#define DBIN 66       // degree bins 0..64 (+pad)

// dst-buckets for the two-pass build: bucket = dst >> 7 (128 nodes each)
#define NB 782        // ceil(100000/128)
#define NBP 784       // padded
#define BCAP 4096     // per-bucket capacity
#define SUBCAP 1024   // per-bank capacity (4 banks; mean ~800, sigma ~28 -> +8 sigma)
#define CHUNK 4096    // edges per bin_edges block
#define NBLK_E ((N_EDGES + CHUNK - 1) / CHUNK)   // 612

#define PERM_NPB 1024 // nodes per perm_scatter block
#define NBLK_P ((N_NODES + PERM_NPB - 1) / PERM_NPB)  // 98

typedef unsigned int uint;
typedef unsigned short ushort;

__device__ inline float bflo(uint w) { return __uint_as_float(w << 16); }
__device__ inline float bfhi(uint w) { return __uint_as_float(w & 0xffff0000u); }
__device__ inline ushort f2bf(float f) {
    uint u = __float_as_uint(f);
    return (ushort)((u + 0x7fffu + ((u >> 16) & 1u)) >> 16);  // RNE
}

// ============ pass 1: coarse-bin edges by dst bucket (dense run writes) =======
__global__ void bin_edges(const int* __restrict__ src, const int* __restrict__ dst,
                          int* __restrict__ gcur, int* __restrict__ binned) {
    __shared__ int scnt[NBP];
    __shared__ int sbase[NBP];
    __shared__ int soff[NBP];
    int t = threadIdx.x;
    for (int i = t; i < NBP; i += 256) { scnt[i] = 0; soff[i] = 0; }
    __syncthreads();
    int base = blockIdx.x * CHUNK;
    int bank = blockIdx.x & 3;
    for (int j = 0; j < CHUNK; j += 256) {
        int e = base + j + t;
        if (e < N_EDGES) atomicAdd(&scnt[dst[e] >> 7], 1);
    }
    __syncthreads();
    for (int b = t; b < NBP; b += 256) {
        int c = scnt[b];
        sbase[b] = (c > 0) ? atomicAdd(&gcur[b * 4 + bank], c) : 0;
    }
    __syncthreads();
    for (int j = 0; j < CHUNK; j += 256) {
        int e = base + j + t;
        if (e < N_EDGES) {
            int d = dst[e];
            int b = d >> 7;
            int pos = sbase[b] + atomicAdd(&soff[b], 1);
            if (pos < SUBCAP)
                binned[b * BCAP + bank * SUBCAP + pos] = (src[e] << 7) | (d & 127);
        }
    }
}

// ============ pass 2: assemble 128x64 slot tile in LDS, stream out; fused deg hist ==
__global__ void build_slots(const int* __restrict__ gcur, const int* __restrict__ binned,
                            int* __restrict__ deg, int* __restrict__ slots,
                            int* __restrict__ dhist) {
    __shared__ int stile[128 * CAP];  // 32 KB
    __shared__ int sdeg[128];
    __shared__ int shist[DBIN];
    int t = threadIdx.x;
    if (t < 128) sdeg[t] = 0;
    if (t < DBIN) shist[t] = 0;
    __syncthreads();
    int b = blockIdx.x;
#pragma unroll
    for (int k = 0; k < 4; ++k) {
        int cnt = gcur[b * 4 + k]; if (cnt > SUBCAP) cnt = SUBCAP;
        const int* seg = binned + b * BCAP + k * SUBCAP;
        for (int i = t; i < cnt; i += 256) {
            int w = seg[i];
            int ld = w & 127, sn = w >> 7;
            int p = atomicAdd(&sdeg[ld], 1);
            if (p < CAP) stile[ld * CAP + p] = sn;
        }
    }
    __syncthreads();
    int nbase = b * 128;
    int rows = N_NODES - nbase; if (rows > 128) rows = 128;
    int total4 = rows * CAP / 4;
    int4* dstp = (int4*)(slots + (size_t)nbase * CAP);
    const int4* srcp = (const int4*)stile;
    for (int i = t; i < total4; i += 256) dstp[i] = srcp[i];
    if (t < rows) {
        int dv = sdeg[t]; if (dv > CAP) dv = CAP;
        deg[nbase + t] = dv;
        atomicAdd(&shist[dv], 1);
    }
    __syncthreads();
    if (t < DBIN && shist[t] > 0) atomicAdd(&dhist[t], shist[t]);
}

// ============ degree scan (tiny, 1 thread) ============
__global__ void deg_scan(const int* __restrict__ dhist, int* __restrict__ dcur) {
    if (threadIdx.x == 0) {
        int run = 0;
        for (int i = 0; i < DBIN; ++i) { dcur[i] = run; run += dhist[i]; }
    }
}

// ============ perm scatter: hierarchical counting-sort by degree ============
// perm[i] = (deg << 17) | node, sorted by degree
__global__ void perm_scatter(const int* __restrict__ deg, int* __restrict__ dcur,
                             int* __restrict__ perm) {
    __shared__ int scnt[DBIN];
    __shared__ int sbase[DBIN];
    __shared__ int soff[DBIN];
    int t = threadIdx.x;
    if (t < DBIN) { scnt[t] = 0; soff[t] = 0; }
    __syncthreads();
    int nbase = blockIdx.x * PERM_NPB;
    for (int j = 0; j < PERM_NPB; j += 256) {
        int n = nbase + j + t;
        if (n < N_NODES) atomicAdd(&scnt[deg[n]], 1);
    }
    __syncthreads();
    if (t < DBIN) {
        int c = scnt[t];
        sbase[t] = (c > 0) ? atomicAdd(&dcur[t], c) : 0;
    }
    __syncthreads();
    for (int j = 0; j < PERM_NPB; j += 256) {
        int n = nbase + j + t;
        if (n < N_NODES) {
            int dv = deg[n];
            int p = sbase[dv] + atomicAdd(&soff[dv], 1);
            perm[p] = (dv << 17) | n;
        }
    }
}

// ============ layer-1 pre-GEMM: tmp(bf16) = x @ W_rel1 (14 -> 32) ============
__global__ void gemm14(const float* __restrict__ h, const float* __restrict__ W,
                       ushort* __restrict__ out) {
    __shared__ float sW[IN_DIM][HID];
    int t = threadIdx.x;
    for (int i = t; i < IN_DIM * HID; i += 256) sW[i / HID][i % HID] = W[i];
    __syncthreads();
    int idx = blockIdx.x * 256 + t;
    if (idx >= N_NODES * HID) return;
    int n = idx >> 5, o = idx & 31;
    const float* hr = h + (long)n * IN_DIM;
    float acc = 0.f;
#pragma unroll
    for (int k = 0; k < IN_DIM; ++k) acc += hr[k] * sW[k][o];
    out[idx] = f2bf(acc);
}

// ============ fused conv: gather(bf16) + (opt) @Wrel + bias + h@Wroot + relu =====
// 4 lanes per node, each owning 8 of 32 features (uint4 = 16B bf16 per edge).
// Nodes processed in degree-sorted order via perm.
template <bool MUL_REL, int K, bool ROOT_BF16>
__global__ void conv_fused(const int* __restrict__ perm, const int* __restrict__ slots,
                           const ushort* __restrict__ featb,  // N x 32 bf16 gather table
                           const void* __restrict__ root_in,  // N x K (bf16 or f32)
                           const float* __restrict__ Wrel,    // 32x32 (if MUL_REL)
                           const float* __restrict__ bias,    // 32
                           const float* __restrict__ Wroot,   // K x 32
                           ushort* __restrict__ outb) {       // N x 32 bf16
    __shared__ float sWrel[MUL_REL ? HID * HID : 1];
    __shared__ float sWroot[K * HID];
    __shared__ float sb[HID];
    int t = threadIdx.x;
    if (MUL_REL)
        for (int i = t; i < HID * HID; i += 256) sWrel[i] = Wrel[i];
    for (int i = t; i < K * HID; i += 256) sWroot[i] = Wroot[i];
    if (t < HID) sb[t] = bias[t];
    __syncthreads();

    int i = blockIdx.x * 64 + (t >> 2);
    if (i >= N_NODES) return;
    int q = t & 3;          // lane in 4-group: owns features q*8 .. q*8+7
    int pw = perm[i];
    int n = pw & 131071;
    int dn = pw >> 17;

    const int* sl = slots + n * CAP;
    float a[8] = {0.f, 0.f, 0.f, 0.f, 0.f, 0.f, 0.f, 0.f};
    int e = 0;
    for (; e + 2 <= dn; e += 2) {
        int c0 = sl[e], c1 = sl[e + 1];
        uint4 v0 = *(const uint4*)(featb + c0 * HID + q * 8);
        uint4 v1 = *(const uint4*)(featb + c1 * HID + q * 8);
        a[0] += bflo(v0.x) + bflo(v1.x);
        a[1] += bfhi(v0.x) + bfhi(v1.x);
        a[2] += bflo(v0.y) + bflo(v1.y);
        a[3] += bfhi(v0.y) + bfhi(v1.y);
        a[4] += bflo(v0.z) + bflo(v1.z);
        a[5] += bfhi(v0.z) + bfhi(v1.z);
        a[6] += bflo(v0.w) + bflo(v1.w);
        a[7] += bfhi(v0.w) + bfhi(v1.w);
    }
    if (e < dn) {
        int c = sl[e];
        uint4 v = *(const uint4*)(featb + c * HID + q * 8);
        a[0] += bflo(v.x); a[1] += bfhi(v.x);
        a[2] += bflo(v.y); a[3] += bfhi(v.y);
        a[4] += bflo(v.z); a[5] += bfhi(v.z);
        a[6] += bflo(v.w); a[7] += bfhi(v.w);
    }

    float r[8];
#pragma unroll
    for (int o = 0; o < 8; ++o) r[o] = sb[q * 8 + o];

    if constexpr (MUL_REL) {
#pragma unroll
        for (int cl = 0; cl < 4; ++cl) {
#pragma unroll
            for (int j = 0; j < 8; ++j) {
                float av = __shfl(a[j], cl, 4);
                const float* w = &sWrel[(cl * 8 + j) * HID + q * 8];
#pragma unroll
                for (int o = 0; o < 8; ++o) r[o] += av * w[o];
            }
        }
    } else {
#pragma unroll
        for (int o = 0; o < 8; ++o) r[o] += a[o];
    }

    if constexpr (ROOT_BF16) {
        uint4 h4 = *(const uint4*)((const ushort*)root_in + n * HID + q * 8);
        float hh[8] = {bflo(h4.x), bfhi(h4.x), bflo(h4.y), bfhi(h4.y),
                       bflo(h4.z), bfhi(h4.z), bflo(h4.w), bfhi(h4.w)};
#pragma unroll
        for (int cl = 0; cl < 4; ++cl) {
#pragma unroll
            for (int j = 0; j < 8; ++j) {
                float hv = __shfl(hh[j], cl, 4);
                const float* w = &sWroot[(cl * 8 + j) * HID + q * 8];
#pragma unroll
                for (int o = 0; o < 8; ++o) r[o] += hv * w[o];
            }
        }
    } else {
        const float* hr = (const float*)root_in + (long)n * K;
#pragma unroll
        for (int k = 0; k < K; ++k) {
            float hv = hr[k];
            const float* w = &sWroot[k * HID + q * 8];
#pragma unroll
            for (int o = 0; o < 8; ++o) r[o] += hv * w[o];
        }
    }

    uint pwd[4];
#pragma unroll
    for (int m = 0; m < 4; ++m)
        pwd[m] = (uint)f2bf(fmaxf(r[2 * m], 0.f)) |
                 ((uint)f2bf(fmaxf(r[2 * m + 1], 0.f)) << 16);
    *(uint4*)(outb + n * HID + q * 8) = make_uint4(pwd[0], pwd[1], pwd[2], pwd[3]);
}

// ============ sum pool per graph (batch sorted -> run-length accumulate) ======
#define POOL_NODES 128
__global__ void pool_sum(const ushort* __restrict__ h, const int* __restrict__ batch,
                         float* __restrict__ g) {
    __shared__ int sbatch[POOL_NODES];
    int t = threadIdx.x;
    int nbase = blockIdx.x * POOL_NODES;
    for (int i = t; i < POOL_NODES; i += 256) {
        int n = nbase + i;
        sbatch[i] = (n < N_NODES) ? batch[n] : -1;
    }
    __syncthreads();
    int f = t & 31;
    int c0 = (t >> 5) * 16;
    int curb = -1;
    float acc = 0.f;
    for (int j = 0; j < 16; ++j) {
        int li = c0 + j;
        int n = nbase + li;
        if (n >= N_NODES) break;
        int bid = sbatch[li];
        float v = bflo((uint)h[(long)n * HID + f]);
        if (bid != curb) {
            if (curb >= 0) atomicAdd(&g[curb * HID + f], acc);
            curb = bid;
            acc = 0.f;
        }
        acc += v;
    }
    if (curb >= 0) atomicAdd(&g[curb * HID + f], acc);
}

// ============ head: relu(g@W1+b1) @ W2 + b2 -> log_softmax ============
__global__ void head(const float* __restrict__ g, const float* __restrict__ w1,
                     const float* __restrict__ b1, const float* __restrict__ w2,
                     const float* __restrict__ b2, float* __restrict__ out) {
    __shared__ float sW1[HID][HID];
    __shared__ float sW2[HID][2];
    __shared__ float sb1[HID];
    int t = threadIdx.x;  // 512 threads, one graph each
    for (int i = t; i < HID * HID; i += 512) sW1[i / HID][i % HID] = w1[i];
    if (t < HID * 2) sW2[t / 2][t % 2] = w2[t];
    if (t < HID) sb1[t] = b1[t];
    __syncthreads();
    float gi[HID];
#pragma unroll
    for (int k = 0; k < HID; ++k) gi[k] = g[t * HID + k];
    float l0 = b2[0], l1 = b2[1];
#pragma unroll
    for (int o = 0; o < HID; ++o) {
        float a = sb1[o];
#pragma unroll
        for (int k = 0; k < HID; ++k) a += gi[k] * sW1[k][o];
        a = fmaxf(a, 0.f);
        l0 += a * sW2[o][0];
        l1 += a * sW2[o][1];
    }
    float m = fmaxf(l0, l1);
    float lse = m + logf(expf(l0 - m) + expf(l1 - m));
    out[t * 2 + 0] = l0 - lse;
    out[t * 2 + 1] = l1 - lse;
}

extern "C" void kernel_launch(void* const* d_in, const int* in_sizes, int n_in,
                              void* d_out, int out_size, void* d_ws, size_t ws_size,
                              hipStream_t stream) {
    const float* x      = (const float*)d_in[0];
    const float* W_rel1 = (const float*)d_in[1];
    const float* b_rel1 = (const float*)d_in[2];
    const float* W_root1= (const float*)d_in[3];
    const float* W_rel  = (const float*)d_in[4];   // 4 x 32 x 32
    const float* b_rel  = (const float*)d_in[5];   // 4 x 32
    const float* W_root = (const float*)d_in[6];   // 4 x 32 x 32
    const float* lin1_w = (const float*)d_in[7];
    const float* lin1_b = (const float*)d_in[8];
    const float* lin2_w = (const float*)d_in[9];
    const float* lin2_b = (const float*)d_in[10];
    const int*   ei     = (const int*)d_in[11];    // [2, E]: src then dst
    const int*   batch  = (const int*)d_in[12];
    float* out = (float*)d_out;

    const int* src = ei;
    const int* dst = ei + N_EDGES;

    // workspace layout (16B alignment preserved at each float4/int4 region)
    int*    gcur   = (int*)d_ws;                        // NBP*4 = 3136, pad 3200
    int*    dhist  = gcur + 3200;                       // DBIN pad 80
    int*    dcur   = dhist + 80;                        // DBIN pad 80
    int*    binned = dcur + 80;                         // NB * BCAP
    int*    deg    = binned + NB * BCAP;                // N pad N+32
    int*    perm   = deg + N_NODES + 32;                // N pad N+32
    int*    slots  = perm + N_NODES + 32;               // N * CAP
    ushort* B0b    = (ushort*)(slots + (size_t)N_NODES * CAP);  // N*32 bf16
    ushort* B1b    = B0b + (size_t)N_NODES * HID;               // N*32 bf16
    float*  g      = (float*)(B1b + (size_t)N_NODES * HID);     // 512*32 f32

    dim3 blk(256);
    dim3 grd_no((N_NODES * HID + 255) / 256);  // 12500
    dim3 grd_cv((N_NODES + 63) / 64);          // 1563
    dim3 grd_pl((N_NODES + POOL_NODES - 1) / POOL_NODES);

    // ---- build: bin -> slots(+hist) -> scan -> perm ----
    hipMemsetAsync(gcur, 0, 3360 * sizeof(int), stream);
    bin_edges<<<dim3(NBLK_E), blk, 0, stream>>>(src, dst, gcur, binned);
    build_slots<<<dim3(NB), blk, 0, stream>>>(gcur, binned, deg, slots, dhist);
    deg_scan<<<dim3(1), dim3(64), 0, stream>>>(dhist, dcur);
    perm_scatter<<<dim3(NBLK_P), blk, 0, stream>>>(deg, dcur, perm);

    // ---- layer 1: tmp = x@W_rel1 (bf16); h1 = relu(gather(tmp) + b1 + x@W_root1) ----
    gemm14<<<grd_no, blk, 0, stream>>>(x, W_rel1, B0b);
    conv_fused<false, IN_DIM, false><<<grd_cv, blk, 0, stream>>>(
        perm, slots, B0b, (const void*)x, nullptr, b_rel1, W_root1, B1b);

    // ---- layers 2..5: h' = relu(gather(h)@W_rel + b + h@W_root) ----
    ushort* cur = B1b;
    ushort* nxt = B0b;
    for (int i = 0; i < 4; ++i) {
        conv_fused<true, HID, true><<<grd_cv, blk, 0, stream>>>(
            perm, slots, cur, (const void*)cur, W_rel + i * HID * HID,
            b_rel + i * HID, W_root + i * HID * HID, nxt);
        ushort* tswap = cur; cur = nxt; nxt = tswap;
    }
    // final h in `cur`

    // ---- sum pool + head ----
    hipMemsetAsync(g, 0, (size_t)N_GRAPHS * HID * sizeof(float), stream);
    pool_sum<<<grd_pl, blk, 0, stream>>>(cur, batch, g);
    head<<<dim3(1), dim3(512), 0, stream>>>(g, lin1_w, lin1_b, lin2_w, lin2_b, out);
}

// Round 7
// 390.505 us; speedup vs baseline: 1.1810x; 1.1810x over previous
//
#include <hip/hip_runtime.h>
#include <math.h>

#define N_NODES 100000
#define N_EDGES 2500000
#define N_GRAPHS 512
#define IN_DIM 14
#define HID 32
#define CAP 64        // per-node slot capacity; degree ~ Poisson(25), max ~55

// dst-buckets for the two-pass build: bucket = dst >> 7 (128 nodes each)
#define NB 782        // ceil(100000/128)
#define NBP 784       // padded
#define BCAP 4096     // per-bucket capacity
#define SUBCAP 1024   // per-bank capacity (4 banks)
#define CHUNK 4096    // edges per bin_edges block
#define NBLK_E ((N_EDGES + CHUNK - 1) / CHUNK)   // 612

typedef unsigned int uint;
typedef unsigned short ushort;

__device__ inline float bflo(uint w) { return __uint_as_float(w << 16); }
__device__ inline float bfhi(uint w) { return __uint_as_float(w & 0xffff0000u); }
__device__ inline ushort f2bf(float f) {
    uint u = __float_as_uint(f);
    return (ushort)((u + 0x7fffu + ((u >> 16) & 1u)) >> 16);  // RNE
}

// ============ pass 1: coarse-bin edges by dst bucket (dense run writes) =======
__global__ void bin_edges(const int* __restrict__ src, const int* __restrict__ dst,
                          int* __restrict__ gcur, int* __restrict__ binned) {
    __shared__ int scnt[NBP];
    __shared__ int sbase[NBP];
    __shared__ int soff[NBP];
    int t = threadIdx.x;
    for (int i = t; i < NBP; i += 256) { scnt[i] = 0; soff[i] = 0; }
    __syncthreads();
    int base = blockIdx.x * CHUNK;
    int bank = blockIdx.x & 3;
    for (int j = 0; j < CHUNK; j += 256) {
        int e = base + j + t;
        if (e < N_EDGES) atomicAdd(&scnt[dst[e] >> 7], 1);
    }
    __syncthreads();
    for (int b = t; b < NBP; b += 256) {
        int c = scnt[b];
        sbase[b] = (c > 0) ? atomicAdd(&gcur[b * 4 + bank], c) : 0;
    }
    __syncthreads();
    for (int j = 0; j < CHUNK; j += 256) {
        int e = base + j + t;
        if (e < N_EDGES) {
            int d = dst[e];
            int b = d >> 7;
            int pos = sbase[b] + atomicAdd(&soff[b], 1);
            if (pos < SUBCAP)
                binned[b * BCAP + bank * SUBCAP + pos] = (src[e] << 7) | (d & 127);
        }
    }
}

// ============ pass 2: assemble 128x64 slot tile in LDS; write only used lines ====
__global__ void build_slots(const int* __restrict__ gcur, const int* __restrict__ binned,
                            int* __restrict__ deg, int* __restrict__ slots) {
    __shared__ int stile[128 * CAP];  // 32 KB
    __shared__ int sdeg[128];
    int t = threadIdx.x;
    if (t < 128) sdeg[t] = 0;
    __syncthreads();
    int b = blockIdx.x;
#pragma unroll
    for (int k = 0; k < 4; ++k) {
        int cnt = gcur[b * 4 + k]; if (cnt > SUBCAP) cnt = SUBCAP;
        const int* seg = binned + b * BCAP + k * SUBCAP;
        for (int i = t; i < cnt; i += 256) {
            int w = seg[i];
            int ld = w & 127, sn = w >> 7;
            int p = atomicAdd(&sdeg[ld], 1);
            if (p < CAP) stile[ld * CAP + p] = sn;
        }
    }
    __syncthreads();
    int nbase = b * 128;
    int rows = N_NODES - nbase; if (rows > 128) rows = 128;
    int r = t & 127, h = t >> 7;           // 2 threads per row
    if (r < rows) {
        int dv = sdeg[r]; if (dv > CAP) dv = CAP;
        if (h == 0) deg[nbase + r] = dv;
        int n4 = ((dv + 15) >> 4) << 2;    // int4 count covering whole 64B lines
        int4* drow = (int4*)(slots + (size_t)(nbase + r) * CAP);
        const int4* srow = (const int4*)(stile + r * CAP);
        for (int i = h; i < n4; i += 2) drow[i] = srow[i];
    }
}

// ============ layer-1 pre-GEMM: tmp(bf16) = x @ W_rel1 (14 -> 32) ============
__global__ void gemm14(const float* __restrict__ h, const float* __restrict__ W,
                       ushort* __restrict__ out) {
    __shared__ float sW[IN_DIM][HID];
    int t = threadIdx.x;
    for (int i = t; i < IN_DIM * HID; i += 256) sW[i / HID][i % HID] = W[i];
    __syncthreads();
    int idx = blockIdx.x * 256 + t;
    if (idx >= N_NODES * HID) return;
    int n = idx >> 5, o = idx & 31;
    const float* hr = h + (long)n * IN_DIM;
    float acc = 0.f;
#pragma unroll
    for (int k = 0; k < IN_DIM; ++k) acc += hr[k] * sW[k][o];
    out[idx] = f2bf(acc);
}

// ============ fused conv: gather(bf16) + (opt) @Wrel + bias + h@Wroot + relu =====
// 8 lanes per node, each owning 4 of 32 features (uint2 = 8B bf16 per edge).
// Slot-preload: 8 slots per coalesced load, shfl-broadcast, 8 independent
// feature loads in flight per round.
template <bool MUL_REL, int K, bool ROOT_BF16>
__global__ void conv_fused(const int* __restrict__ deg, const int* __restrict__ slots,
                           const ushort* __restrict__ featb,  // N x 32 bf16 gather table
                           const void* __restrict__ root_in,  // N x K (bf16 or f32)
                           const float* __restrict__ Wrel,    // 32x32 (if MUL_REL)
                           const float* __restrict__ bias,    // 32
                           const float* __restrict__ Wroot,   // K x 32
                           ushort* __restrict__ outb) {       // N x 32 bf16
    __shared__ float sWrel[MUL_REL ? HID * HID : 1];
    __shared__ float sWroot[K * HID];
    __shared__ float sb[HID];
    int t = threadIdx.x;
    if (MUL_REL)
        for (int i = t; i < HID * HID; i += 256) sWrel[i] = Wrel[i];
    for (int i = t; i < K * HID; i += 256) sWroot[i] = Wroot[i];
    if (t < HID) sb[t] = bias[t];
    __syncthreads();

    int n = blockIdx.x * 32 + (t >> 3);  // 3125 blocks * 32 nodes = 100000 exactly
    int q = t & 7;
    int o = q * 4;

    int dn = deg[n]; if (dn > CAP) dn = CAP;
    const int* sl = slots + n * CAP;
    float a0 = 0.f, a1 = 0.f, a2 = 0.f, a3 = 0.f;
    for (int base = 0; base < dn; base += 8) {
        // coalesced slot preload (clamped: garbage beyond dn never used as addr)
        int my = (base + q < dn) ? sl[base + q] : 0;
#pragma unroll
        for (int j = 0; j < 8; ++j) {
            int c = __shfl(my, j, 8);               // valid row id for all j
            uint2 v = *(const uint2*)(featb + c * HID + o);
            bool ok = (base + j) < dn;
            a0 += ok ? bflo(v.x) : 0.f;
            a1 += ok ? bfhi(v.x) : 0.f;
            a2 += ok ? bflo(v.y) : 0.f;
            a3 += ok ? bfhi(v.y) : 0.f;
        }
    }

    float r0 = sb[o], r1 = sb[o + 1], r2 = sb[o + 2], r3 = sb[o + 3];
    if constexpr (MUL_REL) {
        float a[4] = {a0, a1, a2, a3};
#pragma unroll
        for (int c = 0; c < 8; ++c) {
#pragma unroll
            for (int j = 0; j < 4; ++j) {
                float av = __shfl(a[j], c, 8);
                const float* w = &sWrel[(c * 4 + j) * HID + o];
                r0 += av * w[0]; r1 += av * w[1]; r2 += av * w[2]; r3 += av * w[3];
            }
        }
    } else {
        r0 += a0; r1 += a1; r2 += a2; r3 += a3;
    }

    if constexpr (ROOT_BF16) {
        uint2 h2 = *(const uint2*)((const ushort*)root_in + n * HID + o);
        float hh[4] = {bflo(h2.x), bfhi(h2.x), bflo(h2.y), bfhi(h2.y)};
#pragma unroll
        for (int c = 0; c < 8; ++c) {
#pragma unroll
            for (int j = 0; j < 4; ++j) {
                float hv = __shfl(hh[j], c, 8);
                const float* w = &sWroot[(c * 4 + j) * HID + o];
                r0 += hv * w[0]; r1 += hv * w[1]; r2 += hv * w[2]; r3 += hv * w[3];
            }
        }
    } else {
        const float* hr = (const float*)root_in + (long)n * K;
#pragma unroll
        for (int k = 0; k < K; ++k) {
            float hv = hr[k];
            const float* w = &sWroot[k * HID + o];
            r0 += hv * w[0]; r1 += hv * w[1]; r2 += hv * w[2]; r3 += hv * w[3];
        }
    }

    uint lo = (uint)f2bf(fmaxf(r0, 0.f)) | ((uint)f2bf(fmaxf(r1, 0.f)) << 16);
    uint hi = (uint)f2bf(fmaxf(r2, 0.f)) | ((uint)f2bf(fmaxf(r3, 0.f)) << 16);
    *(uint2*)(outb + n * HID + o) = make_uint2(lo, hi);
}

// ============ sum pool per graph (batch sorted -> run-length accumulate) ======
#define POOL_NODES 128
__global__ void pool_sum(const ushort* __restrict__ h, const int* __restrict__ batch,
                         float* __restrict__ g) {
    __shared__ int sbatch[POOL_NODES];
    int t = threadIdx.x;
    int nbase = blockIdx.x * POOL_NODES;
    for (int i = t; i < POOL_NODES; i += 256) {
        int n = nbase + i;
        sbatch[i] = (n < N_NODES) ? batch[n] : -1;
    }
    __syncthreads();
    int f = t & 31;
    int c0 = (t >> 5) * 16;
    int curb = -1;
    float acc = 0.f;
    for (int j = 0; j < 16; ++j) {
        int li = c0 + j;
        int n = nbase + li;
        if (n >= N_NODES) break;
        int bid = sbatch[li];
        float v = bflo((uint)h[(long)n * HID + f]);
        if (bid != curb) {
            if (curb >= 0) atomicAdd(&g[curb * HID + f], acc);
            curb = bid;
            acc = 0.f;
        }
        acc += v;
    }
    if (curb >= 0) atomicAdd(&g[curb * HID + f], acc);
}

// ============ head: relu(g@W1+b1) @ W2 + b2 -> log_softmax ============
__global__ void head(const float* __restrict__ g, const float* __restrict__ w1,
                     const float* __restrict__ b1, const float* __restrict__ w2,
                     const float* __restrict__ b2, float* __restrict__ out) {
    __shared__ float sW1[HID][HID];
    __shared__ float sW2[HID][2];
    __shared__ float sb1[HID];
    int t = threadIdx.x;  // 512 threads, one graph each
    for (int i = t; i < HID * HID; i += 512) sW1[i / HID][i % HID] = w1[i];
    if (t < HID * 2) sW2[t / 2][t % 2] = w2[t];
    if (t < HID) sb1[t] = b1[t];
    __syncthreads();
    float gi[HID];
#pragma unroll
    for (int k = 0; k < HID; ++k) gi[k] = g[t * HID + k];
    float l0 = b2[0], l1 = b2[1];
#pragma unroll
    for (int o = 0; o < HID; ++o) {
        float a = sb1[o];
#pragma unroll
        for (int k = 0; k < HID; ++k) a += gi[k] * sW1[k][o];
        a = fmaxf(a, 0.f);
        l0 += a * sW2[o][0];
        l1 += a * sW2[o][1];
    }
    float m = fmaxf(l0, l1);
    float lse = m + logf(expf(l0 - m) + expf(l1 - m));
    out[t * 2 + 0] = l0 - lse;
    out[t * 2 + 1] = l1 - lse;
}

extern "C" void kernel_launch(void* const* d_in, const int* in_sizes, int n_in,
                              void* d_out, int out_size, void* d_ws, size_t ws_size,
                              hipStream_t stream) {
    const float* x      = (const float*)d_in[0];
    const float* W_rel1 = (const float*)d_in[1];
    const float* b_rel1 = (const float*)d_in[2];
    const float* W_root1= (const float*)d_in[3];
    const float* W_rel  = (const float*)d_in[4];   // 4 x 32 x 32
    const float* b_rel  = (const float*)d_in[5];   // 4 x 32
    const float* W_root = (const float*)d_in[6];   // 4 x 32 x 32
    const float* lin1_w = (const float*)d_in[7];
    const float* lin1_b = (const float*)d_in[8];
    const float* lin2_w = (const float*)d_in[9];
    const float* lin2_b = (const float*)d_in[10];
    const int*   ei     = (const int*)d_in[11];    // [2, E]: src then dst
    const int*   batch  = (const int*)d_in[12];
    float* out = (float*)d_out;

    const int* src = ei;
    const int* dst = ei + N_EDGES;

    // workspace layout (16B alignment preserved at each int4/uint4 region)
    int*    gcur   = (int*)d_ws;                        // NBP*4 = 3136, pad 3200
    int*    binned = gcur + 3200;                       // NB * BCAP
    int*    deg    = binned + NB * BCAP;                // N pad N+32
    int*    slots  = deg + N_NODES + 32;                // N * CAP
    ushort* B0b    = (ushort*)(slots + (size_t)N_NODES * CAP);  // N*32 bf16
    ushort* B1b    = B0b + (size_t)N_NODES * HID;               // N*32 bf16
    float*  g      = (float*)(B1b + (size_t)N_NODES * HID);     // 512*32 f32

    dim3 blk(256);
    dim3 grd_no((N_NODES * HID + 255) / 256);  // 12500
    dim3 grd_cv(N_NODES / 32);                 // 3125 (exact)
    dim3 grd_pl((N_NODES + POOL_NODES - 1) / POOL_NODES);

    // ---- two-pass slot-table build ----
    hipMemsetAsync(gcur, 0, 3200 * sizeof(int), stream);
    bin_edges<<<dim3(NBLK_E), blk, 0, stream>>>(src, dst, gcur, binned);
    build_slots<<<dim3(NB), blk, 0, stream>>>(gcur, binned, deg, slots);

    // ---- layer 1: tmp = x@W_rel1 (bf16); h1 = relu(gather(tmp) + b1 + x@W_root1) ----
    gemm14<<<grd_no, blk, 0, stream>>>(x, W_rel1, B0b);
    conv_fused<false, IN_DIM, false><<<grd_cv, blk, 0, stream>>>(
        deg, slots, B0b, (const void*)x, nullptr, b_rel1, W_root1, B1b);

    // ---- layers 2..5: h' = relu(gather(h)@W_rel + b + h@W_root) ----
    ushort* cur = B1b;
    ushort* nxt = B0b;
    for (int i = 0; i < 4; ++i) {
        conv_fused<true, HID, true><<<grd_cv, blk, 0, stream>>>(
            deg, slots, cur, (const void*)cur, W_rel + i * HID * HID,
            b_rel + i * HID, W_root + i * HID * HID, nxt);
        ushort* tswap = cur; cur = nxt; nxt = tswap;
    }
    // final h in `cur`

    // ---- sum pool + head ----
    hipMemsetAsync(g, 0, (size_t)N_GRAPHS * HID * sizeof(float), stream);
    pool_sum<<<grd_pl, blk, 0, stream>>>(cur, batch, g);
    head<<<dim3(1), dim3(512), 0, stream>>>(g, lin1_w, lin1_b, lin2_w, lin2_b, out);
}